// Round 1
// baseline (863.782 us; speedup 1.0000x reference)
//
#include <hip/hip_runtime.h>
#include <stdint.h>

#define NUM_LEVELS 16
#define LEVEL_DIM 2
#define BASE_RES 16
#define LOG2_T 19
#define TABLE_SIZE (1u << LOG2_T)
#define TABLE_MASK (TABLE_SIZE - 1u)

__global__ __launch_bounds__(256) void hashenc_kernel(
    const float* __restrict__ x,
    const float* __restrict__ tables,
    float* __restrict__ out,
    int N)
{
    int n = blockIdx.x * blockDim.x + threadIdx.x;
    if (n >= N) return;

    // load point (x is [N,3] row-major; 12B/lane, contiguous across wave)
    float px = x[(size_t)n * 3 + 0];
    float py = x[(size_t)n * 3 + 1];
    float pz = x[(size_t)n * 3 + 2];

    // x = clip((x + 1) / 2, 0, 1 - 1e-6)  (SIZE = 1.0)
    px = fminf(fmaxf((px + 1.0f) * 0.5f, 0.0f), 1.0f - 1e-6f);
    py = fminf(fmaxf((py + 1.0f) * 0.5f, 0.0f), 1.0f - 1e-6f);
    pz = fminf(fmaxf((pz + 1.0f) * 0.5f, 0.0f), 1.0f - 1e-6f);

    float* op = out + (size_t)n * (NUM_LEVELS * LEVEL_DIM);

    #pragma unroll 4
    for (int l = 0; l < NUM_LEVELS; ++l) {
        float res = (float)(BASE_RES << l);   // exact in f32 up to 524288
        float sx = px * res;
        float sy = py * res;
        float sz = pz * res;
        float fx = floorf(sx);
        float fy = floorf(sy);
        float fz = floorf(sz);
        float tx = sx - fx;
        float ty = sy - fy;
        float tz = sz - fz;
        uint32_t ix = (uint32_t)(int32_t)fx;
        uint32_t iy = (uint32_t)(int32_t)fy;
        uint32_t iz = (uint32_t)(int32_t)fz;

        const float* tb = tables + (size_t)l * TABLE_SIZE * LEVEL_DIM;

        // hash components for both corner values along each axis
        uint32_t hx0 = ix;                          // * 1
        uint32_t hx1 = ix + 1u;
        uint32_t hy0 = iy * 2654435761u;
        uint32_t hy1 = (iy + 1u) * 2654435761u;
        uint32_t hz0 = iz * 805459861u;
        uint32_t hz1 = (iz + 1u) * 805459861u;
        uint32_t lv = (uint32_t)l;

        // compute all 8 indices up front so the 8 gathers issue back-to-back
        uint32_t idx0 = ((hx0 ^ hy0 ^ hz0 ^ lv) & TABLE_MASK) * 2u;
        uint32_t idx1 = ((hx0 ^ hy0 ^ hz1 ^ lv) & TABLE_MASK) * 2u;
        uint32_t idx2 = ((hx0 ^ hy1 ^ hz0 ^ lv) & TABLE_MASK) * 2u;
        uint32_t idx3 = ((hx0 ^ hy1 ^ hz1 ^ lv) & TABLE_MASK) * 2u;
        uint32_t idx4 = ((hx1 ^ hy0 ^ hz0 ^ lv) & TABLE_MASK) * 2u;
        uint32_t idx5 = ((hx1 ^ hy0 ^ hz1 ^ lv) & TABLE_MASK) * 2u;
        uint32_t idx6 = ((hx1 ^ hy1 ^ hz0 ^ lv) & TABLE_MASK) * 2u;
        uint32_t idx7 = ((hx1 ^ hy1 ^ hz1 ^ lv) & TABLE_MASK) * 2u;

        float2 e0 = *(const float2*)(tb + idx0);
        float2 e1 = *(const float2*)(tb + idx1);
        float2 e2 = *(const float2*)(tb + idx2);
        float2 e3 = *(const float2*)(tb + idx3);
        float2 e4 = *(const float2*)(tb + idx4);
        float2 e5 = *(const float2*)(tb + idx5);
        float2 e6 = *(const float2*)(tb + idx6);
        float2 e7 = *(const float2*)(tb + idx7);

        float wx0 = 1.0f - tx, wx1 = tx;
        float wy0 = 1.0f - ty, wy1 = ty;
        float wz0 = 1.0f - tz, wz1 = tz;

        // weights in reference order: prod over (dim0, dim1, dim2)
        float w0 = wx0 * wy0 * wz0;
        float w1 = wx0 * wy0 * wz1;
        float w2 = wx0 * wy1 * wz0;
        float w3 = wx0 * wy1 * wz1;
        float w4 = wx1 * wy0 * wz0;
        float w5 = wx1 * wy0 * wz1;
        float w6 = wx1 * wy1 * wz0;
        float w7 = wx1 * wy1 * wz1;

        float a0 = e0.x * w0 + e1.x * w1 + e2.x * w2 + e3.x * w3
                 + e4.x * w4 + e5.x * w5 + e6.x * w6 + e7.x * w7;
        float a1 = e0.y * w0 + e1.y * w1 + e2.y * w2 + e3.y * w3
                 + e4.y * w4 + e5.y * w5 + e6.y * w6 + e7.y * w7;

        *(float2*)(op + l * 2) = make_float2(a0, a1);
    }
}

extern "C" void kernel_launch(void* const* d_in, const int* in_sizes, int n_in,
                              void* d_out, int out_size, void* d_ws, size_t ws_size,
                              hipStream_t stream) {
    const float* x      = (const float*)d_in[0];
    const float* tables = (const float*)d_in[1];
    float* out          = (float*)d_out;
    int N = in_sizes[0] / 3;

    int block = 256;
    int grid = (N + block - 1) / block;
    hashenc_kernel<<<grid, block, 0, stream>>>(x, tables, out, N);
}

// Round 2
// 561.212 us; speedup vs baseline: 1.5391x; 1.5391x over previous
//
#include <hip/hip_runtime.h>
#include <stdint.h>

#define NUM_LEVELS 16
#define LEVEL_DIM 2
#define BASE_RES 16
#define LOG2_T 19
#define TABLE_SIZE (1u << LOG2_T)
#define TABLE_MASK (TABLE_SIZE - 1u)

#define CPL 256      // chunk-blocks per level (8*CPL = 2048 = resident-block capacity)
#define BLOCK 256

typedef float v2f __attribute__((ext_vector_type(2)));
typedef float v4f __attribute__((ext_vector_type(4)));

// ---------------- Phase 1: level-sharded gather ----------------
// blockIdx % 8 -> XCD (dispatch round-robin heuristic). Levels 0..7 run first
// (blocks 0..8*CPL-1), then levels 8..15, so each XCD's 4MB L2 holds exactly
// one 4MB table at a time.
__global__ __launch_bounds__(256, 8) void gather_level_kernel(
    const float* __restrict__ x,
    const float* __restrict__ tables,
    float* __restrict__ ws,      // [NUM_LEVELS][N] float2, level-major
    int N)
{
    int g = blockIdx.x;
    int half  = g / (8 * CPL);          // 0 or 1
    int h     = g % (8 * CPL);
    int level = (h & 7) + 8 * half;
    int chunk = h >> 3;
    int P     = (N + CPL - 1) / CPL;    // points per chunk
    int base  = chunk * P;

    const float* tb = tables + (size_t)level * TABLE_SIZE * LEVEL_DIM;
    v2f* wrow = (v2f*)ws + (size_t)level * N;
    float res = (float)(BASE_RES << level);
    uint32_t lv = (uint32_t)level;

    for (int i = threadIdx.x; i < P; i += BLOCK) {
        int n = base + i;
        if (n >= N) break;

        // x is streamed (re-read once per level) -> non-temporal, don't evict table
        float px = __builtin_nontemporal_load(x + (size_t)n * 3 + 0);
        float py = __builtin_nontemporal_load(x + (size_t)n * 3 + 1);
        float pz = __builtin_nontemporal_load(x + (size_t)n * 3 + 2);

        px = fminf(fmaxf((px + 1.0f) * 0.5f, 0.0f), 1.0f - 1e-6f);
        py = fminf(fmaxf((py + 1.0f) * 0.5f, 0.0f), 1.0f - 1e-6f);
        pz = fminf(fmaxf((pz + 1.0f) * 0.5f, 0.0f), 1.0f - 1e-6f);

        float sx = px * res, sy = py * res, sz = pz * res;
        float fx = floorf(sx), fy = floorf(sy), fz = floorf(sz);
        float tx = sx - fx, ty = sy - fy, tz = sz - fz;
        uint32_t ix = (uint32_t)(int32_t)fx;
        uint32_t iy = (uint32_t)(int32_t)fy;
        uint32_t iz = (uint32_t)(int32_t)fz;

        uint32_t hx0 = ix;
        uint32_t hx1 = ix + 1u;
        uint32_t hy0 = iy * 2654435761u;
        uint32_t hy1 = (iy + 1u) * 2654435761u;
        uint32_t hz0 = iz * 805459861u;
        uint32_t hz1 = (iz + 1u) * 805459861u;

        uint32_t idx0 = ((hx0 ^ hy0 ^ hz0 ^ lv) & TABLE_MASK) * 2u;
        uint32_t idx1 = ((hx0 ^ hy0 ^ hz1 ^ lv) & TABLE_MASK) * 2u;
        uint32_t idx2 = ((hx0 ^ hy1 ^ hz0 ^ lv) & TABLE_MASK) * 2u;
        uint32_t idx3 = ((hx0 ^ hy1 ^ hz1 ^ lv) & TABLE_MASK) * 2u;
        uint32_t idx4 = ((hx1 ^ hy0 ^ hz0 ^ lv) & TABLE_MASK) * 2u;
        uint32_t idx5 = ((hx1 ^ hy0 ^ hz1 ^ lv) & TABLE_MASK) * 2u;
        uint32_t idx6 = ((hx1 ^ hy1 ^ hz0 ^ lv) & TABLE_MASK) * 2u;
        uint32_t idx7 = ((hx1 ^ hy1 ^ hz1 ^ lv) & TABLE_MASK) * 2u;

        v2f e0 = *(const v2f*)(tb + idx0);
        v2f e1 = *(const v2f*)(tb + idx1);
        v2f e2 = *(const v2f*)(tb + idx2);
        v2f e3 = *(const v2f*)(tb + idx3);
        v2f e4 = *(const v2f*)(tb + idx4);
        v2f e5 = *(const v2f*)(tb + idx5);
        v2f e6 = *(const v2f*)(tb + idx6);
        v2f e7 = *(const v2f*)(tb + idx7);

        float wx0 = 1.0f - tx, wx1 = tx;
        float wy0 = 1.0f - ty, wy1 = ty;
        float wz0 = 1.0f - tz, wz1 = tz;

        float w0 = wx0 * wy0 * wz0;
        float w1 = wx0 * wy0 * wz1;
        float w2 = wx0 * wy1 * wz0;
        float w3 = wx0 * wy1 * wz1;
        float w4 = wx1 * wy0 * wz0;
        float w5 = wx1 * wy0 * wz1;
        float w6 = wx1 * wy1 * wz0;
        float w7 = wx1 * wy1 * wz1;

        v2f acc;
        acc.x = e0.x * w0 + e1.x * w1 + e2.x * w2 + e3.x * w3
              + e4.x * w4 + e5.x * w5 + e6.x * w6 + e7.x * w7;
        acc.y = e0.y * w0 + e1.y * w1 + e2.y * w2 + e3.y * w3
              + e4.y * w4 + e5.y * w5 + e6.y * w6 + e7.y * w7;

        __builtin_nontemporal_store(acc, wrow + n);
    }
}

// ---------------- Phase 2: [L][N][2] -> [N][L*2] transpose ----------------
// Reads coalesced (per level, consecutive n); each thread writes its full
// 128B output row with 8 dwordx4 -> full-line writebacks, no amplification.
__global__ __launch_bounds__(256) void transpose_kernel(
    const float* __restrict__ ws, float* __restrict__ out, int N)
{
    int n = blockIdx.x * blockDim.x + threadIdx.x;
    if (n >= N) return;

    v2f v[NUM_LEVELS];
    #pragma unroll
    for (int l = 0; l < NUM_LEVELS; ++l)
        v[l] = __builtin_nontemporal_load((const v2f*)ws + (size_t)l * N + n);

    v4f* o = (v4f*)(out + (size_t)n * (NUM_LEVELS * LEVEL_DIM));
    #pragma unroll
    for (int i = 0; i < 8; ++i) {
        v4f t;
        t.x = v[2 * i].x;     t.y = v[2 * i].y;
        t.z = v[2 * i + 1].x; t.w = v[2 * i + 1].y;
        __builtin_nontemporal_store(t, o + i);
    }
}

// ---------------- Fallback: point-major (round-1 kernel, passing) ----------
__global__ __launch_bounds__(256) void hashenc_fallback(
    const float* __restrict__ x, const float* __restrict__ tables,
    float* __restrict__ out, int N)
{
    int n = blockIdx.x * blockDim.x + threadIdx.x;
    if (n >= N) return;
    float px = x[(size_t)n * 3 + 0];
    float py = x[(size_t)n * 3 + 1];
    float pz = x[(size_t)n * 3 + 2];
    px = fminf(fmaxf((px + 1.0f) * 0.5f, 0.0f), 1.0f - 1e-6f);
    py = fminf(fmaxf((py + 1.0f) * 0.5f, 0.0f), 1.0f - 1e-6f);
    pz = fminf(fmaxf((pz + 1.0f) * 0.5f, 0.0f), 1.0f - 1e-6f);
    float* op = out + (size_t)n * (NUM_LEVELS * LEVEL_DIM);
    #pragma unroll 4
    for (int l = 0; l < NUM_LEVELS; ++l) {
        float res = (float)(BASE_RES << l);
        float sx = px * res, sy = py * res, sz = pz * res;
        float fx = floorf(sx), fy = floorf(sy), fz = floorf(sz);
        float tx = sx - fx, ty = sy - fy, tz = sz - fz;
        uint32_t ix = (uint32_t)(int32_t)fx, iy = (uint32_t)(int32_t)fy, iz = (uint32_t)(int32_t)fz;
        const float* tb = tables + (size_t)l * TABLE_SIZE * LEVEL_DIM;
        uint32_t hx0 = ix, hx1 = ix + 1u;
        uint32_t hy0 = iy * 2654435761u, hy1 = (iy + 1u) * 2654435761u;
        uint32_t hz0 = iz * 805459861u, hz1 = (iz + 1u) * 805459861u;
        uint32_t lv = (uint32_t)l;
        uint32_t idx0 = ((hx0 ^ hy0 ^ hz0 ^ lv) & TABLE_MASK) * 2u;
        uint32_t idx1 = ((hx0 ^ hy0 ^ hz1 ^ lv) & TABLE_MASK) * 2u;
        uint32_t idx2 = ((hx0 ^ hy1 ^ hz0 ^ lv) & TABLE_MASK) * 2u;
        uint32_t idx3 = ((hx0 ^ hy1 ^ hz1 ^ lv) & TABLE_MASK) * 2u;
        uint32_t idx4 = ((hx1 ^ hy0 ^ hz0 ^ lv) & TABLE_MASK) * 2u;
        uint32_t idx5 = ((hx1 ^ hy0 ^ hz1 ^ lv) & TABLE_MASK) * 2u;
        uint32_t idx6 = ((hx1 ^ hy1 ^ hz0 ^ lv) & TABLE_MASK) * 2u;
        uint32_t idx7 = ((hx1 ^ hy1 ^ hz1 ^ lv) & TABLE_MASK) * 2u;
        float2 e0 = *(const float2*)(tb + idx0);
        float2 e1 = *(const float2*)(tb + idx1);
        float2 e2 = *(const float2*)(tb + idx2);
        float2 e3 = *(const float2*)(tb + idx3);
        float2 e4 = *(const float2*)(tb + idx4);
        float2 e5 = *(const float2*)(tb + idx5);
        float2 e6 = *(const float2*)(tb + idx6);
        float2 e7 = *(const float2*)(tb + idx7);
        float wx0 = 1.0f - tx, wx1 = tx, wy0 = 1.0f - ty, wy1 = ty, wz0 = 1.0f - tz, wz1 = tz;
        float w0 = wx0 * wy0 * wz0, w1 = wx0 * wy0 * wz1, w2 = wx0 * wy1 * wz0, w3 = wx0 * wy1 * wz1;
        float w4 = wx1 * wy0 * wz0, w5 = wx1 * wy0 * wz1, w6 = wx1 * wy1 * wz0, w7 = wx1 * wy1 * wz1;
        float a0 = e0.x*w0 + e1.x*w1 + e2.x*w2 + e3.x*w3 + e4.x*w4 + e5.x*w5 + e6.x*w6 + e7.x*w7;
        float a1 = e0.y*w0 + e1.y*w1 + e2.y*w2 + e3.y*w3 + e4.y*w4 + e5.y*w5 + e6.y*w6 + e7.y*w7;
        *(float2*)(op + l * 2) = make_float2(a0, a1);
    }
}

extern "C" void kernel_launch(void* const* d_in, const int* in_sizes, int n_in,
                              void* d_out, int out_size, void* d_ws, size_t ws_size,
                              hipStream_t stream) {
    const float* x      = (const float*)d_in[0];
    const float* tables = (const float*)d_in[1];
    float* out          = (float*)d_out;
    int N = in_sizes[0] / 3;

    size_t ws_needed = (size_t)NUM_LEVELS * N * LEVEL_DIM * sizeof(float);
    if (ws_size >= ws_needed) {
        float* ws = (float*)d_ws;
        gather_level_kernel<<<NUM_LEVELS * CPL, BLOCK, 0, stream>>>(x, tables, ws, N);
        transpose_kernel<<<(N + BLOCK - 1) / BLOCK, BLOCK, 0, stream>>>(ws, out, N);
    } else {
        hashenc_fallback<<<(N + BLOCK - 1) / BLOCK, BLOCK, 0, stream>>>(x, tables, out, N);
    }
}

// Round 3
// 433.876 us; speedup vs baseline: 1.9909x; 1.2935x over previous
//
#include <hip/hip_runtime.h>
#include <stdint.h>

#define NUM_LEVELS 16
#define LEVEL_DIM 2
#define BASE_RES 16
#define LOG2_T 19
#define TABLE_SIZE (1u << LOG2_T)
#define TABLE_MASK (TABLE_SIZE - 1u)

#define CPL 256      // chunk-blocks per level (8*CPL = 2048 = resident-block capacity)
#define BLOCK 256

typedef float v2f __attribute__((ext_vector_type(2)));
typedef float v4f __attribute__((ext_vector_type(4)));

// Compute one point's interpolated embedding for one level.
// Marked forceinline so two calls' 16 gathers interleave for MLP.
__device__ __forceinline__ v2f encode_point(
    const float* __restrict__ x, const float* __restrict__ tb,
    int n, float res, uint32_t lv)
{
    float px = __builtin_nontemporal_load(x + (size_t)n * 3 + 0);
    float py = __builtin_nontemporal_load(x + (size_t)n * 3 + 1);
    float pz = __builtin_nontemporal_load(x + (size_t)n * 3 + 2);

    px = fminf(fmaxf((px + 1.0f) * 0.5f, 0.0f), 1.0f - 1e-6f);
    py = fminf(fmaxf((py + 1.0f) * 0.5f, 0.0f), 1.0f - 1e-6f);
    pz = fminf(fmaxf((pz + 1.0f) * 0.5f, 0.0f), 1.0f - 1e-6f);

    float sx = px * res, sy = py * res, sz = pz * res;
    float fx = floorf(sx), fy = floorf(sy), fz = floorf(sz);
    float tx = sx - fx, ty = sy - fy, tz = sz - fz;
    uint32_t ix = (uint32_t)(int32_t)fx;
    uint32_t iy = (uint32_t)(int32_t)fy;
    uint32_t iz = (uint32_t)(int32_t)fz;

    uint32_t hx0 = ix;
    uint32_t hx1 = ix + 1u;
    uint32_t hy0 = iy * 2654435761u;
    uint32_t hy1 = (iy + 1u) * 2654435761u;
    uint32_t hz0 = iz * 805459861u;
    uint32_t hz1 = (iz + 1u) * 805459861u;

    uint32_t idx0 = ((hx0 ^ hy0 ^ hz0 ^ lv) & TABLE_MASK) * 2u;
    uint32_t idx1 = ((hx0 ^ hy0 ^ hz1 ^ lv) & TABLE_MASK) * 2u;
    uint32_t idx2 = ((hx0 ^ hy1 ^ hz0 ^ lv) & TABLE_MASK) * 2u;
    uint32_t idx3 = ((hx0 ^ hy1 ^ hz1 ^ lv) & TABLE_MASK) * 2u;
    uint32_t idx4 = ((hx1 ^ hy0 ^ hz0 ^ lv) & TABLE_MASK) * 2u;
    uint32_t idx5 = ((hx1 ^ hy0 ^ hz1 ^ lv) & TABLE_MASK) * 2u;
    uint32_t idx6 = ((hx1 ^ hy1 ^ hz0 ^ lv) & TABLE_MASK) * 2u;
    uint32_t idx7 = ((hx1 ^ hy1 ^ hz1 ^ lv) & TABLE_MASK) * 2u;

    v2f e0 = *(const v2f*)(tb + idx0);
    v2f e1 = *(const v2f*)(tb + idx1);
    v2f e2 = *(const v2f*)(tb + idx2);
    v2f e3 = *(const v2f*)(tb + idx3);
    v2f e4 = *(const v2f*)(tb + idx4);
    v2f e5 = *(const v2f*)(tb + idx5);
    v2f e6 = *(const v2f*)(tb + idx6);
    v2f e7 = *(const v2f*)(tb + idx7);

    float wx0 = 1.0f - tx, wx1 = tx;
    float wy0 = 1.0f - ty, wy1 = ty;
    float wz0 = 1.0f - tz, wz1 = tz;

    float w0 = wx0 * wy0 * wz0;
    float w1 = wx0 * wy0 * wz1;
    float w2 = wx0 * wy1 * wz0;
    float w3 = wx0 * wy1 * wz1;
    float w4 = wx1 * wy0 * wz0;
    float w5 = wx1 * wy0 * wz1;
    float w6 = wx1 * wy1 * wz0;
    float w7 = wx1 * wy1 * wz1;

    v2f acc;
    acc.x = e0.x * w0 + e1.x * w1 + e2.x * w2 + e3.x * w3
          + e4.x * w4 + e5.x * w5 + e6.x * w6 + e7.x * w7;
    acc.y = e0.y * w0 + e1.y * w1 + e2.y * w2 + e3.y * w3
          + e4.y * w4 + e5.y * w5 + e6.y * w6 + e7.y * w7;
    return acc;
}

// ---------------- Phase 1: level-sharded gather ----------------
// blockIdx % 8 -> XCD (dispatch round-robin). Levels 0..7 run first
// (blocks 0..2047), then 8..15; each XCD's 4MB L2 holds exactly one table.
__global__ __launch_bounds__(256, 8) void gather_level_kernel(
    const float* __restrict__ x,
    const float* __restrict__ tables,
    float* __restrict__ ws,      // [NUM_LEVELS][N] float2, level-major
    int N)
{
    int g = blockIdx.x;
    int half  = g / (8 * CPL);          // 0 or 1
    int h     = g % (8 * CPL);
    int level = (h & 7) + 8 * half;
    int chunk = h >> 3;
    int P     = (N + CPL - 1) / CPL;    // points per chunk
    int base  = chunk * P;

    const float* tb = tables + (size_t)level * TABLE_SIZE * LEVEL_DIM;
    v2f* wrow = (v2f*)ws + (size_t)level * N;
    float res = (float)(BASE_RES << level);
    uint32_t lv = (uint32_t)level;

    // 2 points per lane per iteration -> 16 outstanding gathers/wave
    for (int i = threadIdx.x; i < P; i += 2 * BLOCK) {
        int n0 = base + i;
        int n1 = base + i + BLOCK;
        bool ok0 = (n0 < N);
        bool ok1 = (i + BLOCK < P) && (n1 < N);

        if (ok0 && ok1) {
            v2f a0 = encode_point(x, tb, n0, res, lv);
            v2f a1 = encode_point(x, tb, n1, res, lv);
            __builtin_nontemporal_store(a0, wrow + n0);
            __builtin_nontemporal_store(a1, wrow + n1);
        } else if (ok0) {
            v2f a0 = encode_point(x, tb, n0, res, lv);
            __builtin_nontemporal_store(a0, wrow + n0);
        }
    }
}

// ---------------- Phase 2: [L][N][2] -> [N][L*2] transpose ----------------
// NT loads (ws has no reuse); PLAIN stores so the 8 x 16B per-thread stores
// merge into full 128B lines in L2 before writeback (NT 16B stores caused
// partial-line HBM writes -> ~8x write amplification).
__global__ __launch_bounds__(256) void transpose_kernel(
    const float* __restrict__ ws, float* __restrict__ out, int N)
{
    int n = blockIdx.x * blockDim.x + threadIdx.x;
    if (n >= N) return;

    v2f v[NUM_LEVELS];
    #pragma unroll
    for (int l = 0; l < NUM_LEVELS; ++l)
        v[l] = __builtin_nontemporal_load((const v2f*)ws + (size_t)l * N + n);

    v4f* o = (v4f*)(out + (size_t)n * (NUM_LEVELS * LEVEL_DIM));
    #pragma unroll
    for (int i = 0; i < 8; ++i) {
        v4f t;
        t.x = v[2 * i].x;     t.y = v[2 * i].y;
        t.z = v[2 * i + 1].x; t.w = v[2 * i + 1].y;
        o[i] = t;
    }
}

// ---------------- Fallback: point-major (round-1 kernel, passing) ----------
__global__ __launch_bounds__(256) void hashenc_fallback(
    const float* __restrict__ x, const float* __restrict__ tables,
    float* __restrict__ out, int N)
{
    int n = blockIdx.x * blockDim.x + threadIdx.x;
    if (n >= N) return;
    float* op = out + (size_t)n * (NUM_LEVELS * LEVEL_DIM);
    #pragma unroll 4
    for (int l = 0; l < NUM_LEVELS; ++l) {
        const float* tb = tables + (size_t)l * TABLE_SIZE * LEVEL_DIM;
        v2f a = encode_point(x, tb, n, (float)(BASE_RES << l), (uint32_t)l);
        *(v2f*)(op + l * 2) = a;
    }
}

extern "C" void kernel_launch(void* const* d_in, const int* in_sizes, int n_in,
                              void* d_out, int out_size, void* d_ws, size_t ws_size,
                              hipStream_t stream) {
    const float* x      = (const float*)d_in[0];
    const float* tables = (const float*)d_in[1];
    float* out          = (float*)d_out;
    int N = in_sizes[0] / 3;

    size_t ws_needed = (size_t)NUM_LEVELS * N * LEVEL_DIM * sizeof(float);
    if (ws_size >= ws_needed) {
        float* ws = (float*)d_ws;
        gather_level_kernel<<<NUM_LEVELS * CPL, BLOCK, 0, stream>>>(x, tables, ws, N);
        transpose_kernel<<<(N + BLOCK - 1) / BLOCK, BLOCK, 0, stream>>>(ws, out, N);
    } else {
        hashenc_fallback<<<(N + BLOCK - 1) / BLOCK, BLOCK, 0, stream>>>(x, tables, out, N);
    }
}